// Round 2
// baseline (570.323 us; speedup 1.0000x reference)
//
#include <hip/hip_runtime.h>

// y[b,s,n] = sum_k x[b,s,k] * (wq[n,k]*scale[blk]) + bias[n]
// M = 8192, N = 4096, K = 4096, fp32 in/out.
// R2: fused single-dispatch convert (x->bf16, w dequant->bf16), GEMM BK=64
// (two [128][32] sub-tiles per barrier -> half the barrier drains of R1).

#define M_DIM 8192
#define N_DIM 4096
#define K_DIM 4096

typedef short s16x8 __attribute__((ext_vector_type(8)));   // 8 bf16 in 4 VGPRs
typedef float f32x4 __attribute__((ext_vector_type(4)));

__device__ __forceinline__ unsigned short f32_to_bf16(float f) {
    unsigned int u = __float_as_uint(f);
    unsigned int r = (u + 0x7fffu + ((u >> 16) & 1u)) >> 16;   // RNE
    return (unsigned short)r;
}

// ---- fused pre-pass: blocks [0,16384) convert x; [16384,24576) dequant w ----
__global__ __launch_bounds__(256) void cvt_fused_kernel(
    const float4* __restrict__ x, const float4* __restrict__ wq,
    const float* __restrict__ scales,
    s16x8* __restrict__ xo, s16x8* __restrict__ wo) {
    const int b = blockIdx.x;
    const int t = threadIdx.x;
    if (b < 16384) {
        const int i = b * 256 + t;
        float4 a = x[2 * i];
        float4 c = x[2 * i + 1];
        s16x8 r;
        r[0] = (short)f32_to_bf16(a.x); r[1] = (short)f32_to_bf16(a.y);
        r[2] = (short)f32_to_bf16(a.z); r[3] = (short)f32_to_bf16(a.w);
        r[4] = (short)f32_to_bf16(c.x); r[5] = (short)f32_to_bf16(c.y);
        r[6] = (short)f32_to_bf16(c.z); r[7] = (short)f32_to_bf16(c.w);
        xo[i] = r;
    } else {
        const int i = (b - 16384) * 256 + t;
        const float s = scales[i >> 4];   // 8*i/128
        float4 a = wq[2 * i];
        float4 c = wq[2 * i + 1];
        s16x8 r;
        r[0] = (short)f32_to_bf16(a.x * s); r[1] = (short)f32_to_bf16(a.y * s);
        r[2] = (short)f32_to_bf16(a.z * s); r[3] = (short)f32_to_bf16(a.w * s);
        r[4] = (short)f32_to_bf16(c.x * s); r[5] = (short)f32_to_bf16(c.y * s);
        r[6] = (short)f32_to_bf16(c.z * s); r[7] = (short)f32_to_bf16(c.w * s);
        wo[i] = r;
    }
}

// ---- async 16B global -> LDS ----
__device__ __forceinline__ void async_copy16(const unsigned short* g, unsigned short* l) {
    __builtin_amdgcn_global_load_lds(
        (const __attribute__((address_space(1))) unsigned int*)g,
        (__attribute__((address_space(3))) unsigned int*)l,
        16, 0, 0);
}

// ---- GEMM: C[M,N] = A[M,K](bf16) * B[N,K]^T(bf16) + bias ----
// 256 thr = 4 waves 2x2 over 128x128 tile; wave: 4x4 of 16x16x32 MFMA.
// BK=64 as two sequential [128][32] sub-tiles -> one barrier per 64 K.
__global__ __launch_bounds__(256) void gemm_bt_kernel(
    const unsigned short* __restrict__ A,   // M x K bf16 bits
    const unsigned short* __restrict__ B,   // N x K bf16 bits
    const float* __restrict__ bias,         // N
    float* __restrict__ C)                  // M x N
{
    __shared__ unsigned short lds_a[2][128 * 32];   // 16 KB
    __shared__ unsigned short lds_b[2][128 * 32];   // 16 KB

    const int t = threadIdx.x;
    const int w = t >> 6;
    const int l = t & 63;
    const int m0 = blockIdx.y * 128;
    const int n0 = blockIdx.x * 128;
    const int wm = (w & 1) * 64;
    const int wn = (w >> 1) * 64;

    // staging: per call, lane t stages 16B; row = t>>2, chunk = t&3 (8 bf16)
    const int srow = t >> 2;
    const int scol = (t & 3) * 8;
    const unsigned short* gA = A + (long)(m0 + srow) * K_DIM + scol;
    const unsigned short* gB = B + (long)(n0 + srow) * K_DIM + scol;
    unsigned short* lA0 = &lds_a[0][t * 8];
    unsigned short* lA1 = &lds_a[1][t * 8];
    unsigned short* lB0 = &lds_b[0][t * 8];
    unsigned short* lB1 = &lds_b[1][t * 8];

    // fragment addressing (measured m89/m91): row = base+(l&15), k = (l>>4)*8 + j
    const int fr = l & 15;
    const int fc = (l >> 4) * 8;

    f32x4 acc[4][4] = {};

    for (int kt = 0; kt < K_DIM / 64; ++kt) {
        const unsigned short* ga = gA + kt * 64;
        const unsigned short* gb = gB + kt * 64;
        // sub-tile 0 (k .. k+31)
        async_copy16(ga,              lA0);
        async_copy16(ga + 64 * K_DIM, lA0 + 2048);
        async_copy16(gb,              lB0);
        async_copy16(gb + 64 * K_DIM, lB0 + 2048);
        // sub-tile 1 (k+32 .. k+63)
        async_copy16(ga + 32,              lA1);
        async_copy16(ga + 32 + 64 * K_DIM, lA1 + 2048);
        async_copy16(gb + 32,              lB1);
        async_copy16(gb + 32 + 64 * K_DIM, lB1 + 2048);
        __syncthreads();   // drains vmcnt + lgkmcnt

#pragma unroll
        for (int s = 0; s < 2; ++s) {
            s16x8 af[4], bf[4];
#pragma unroll
            for (int i = 0; i < 4; ++i)
                af[i] = *(const s16x8*)(&lds_a[s][(wm + i * 16 + fr) * 32 + fc]);
#pragma unroll
            for (int j = 0; j < 4; ++j)
                bf[j] = *(const s16x8*)(&lds_b[s][(wn + j * 16 + fr) * 32 + fc]);

#pragma unroll
            for (int i = 0; i < 4; ++i)
#pragma unroll
                for (int j = 0; j < 4; ++j)
                    acc[i][j] = __builtin_amdgcn_mfma_f32_16x16x32_bf16(
                        af[i], bf[j], acc[i][j], 0, 0, 0);
        }
        __syncthreads();
    }

    // epilogue: C/D layout row=(l>>4)*4+reg, col=l&15 (measured m89/m91)
    const int q = l >> 4;
#pragma unroll
    for (int j = 0; j < 4; ++j) {
        const int col = n0 + wn + j * 16 + (l & 15);
        const float bv = bias[col];
#pragma unroll
        for (int i = 0; i < 4; ++i) {
            const int row = m0 + wm + i * 16 + q * 4;
#pragma unroll
            for (int r = 0; r < 4; ++r) {
                C[(long)(row + r) * N_DIM + col] = acc[i][j][r] + bv;
            }
        }
    }
}

extern "C" void kernel_launch(void* const* d_in, const int* in_sizes, int n_in,
                              void* d_out, int out_size, void* d_ws, size_t ws_size,
                              hipStream_t stream) {
    const float* x      = (const float*)d_in[0];
    const float* wq     = (const float*)d_in[1];
    const float* scales = (const float*)d_in[2];
    const float* bias   = (const float*)d_in[3];
    float* out = (float*)d_out;

    unsigned short* x_bf = (unsigned short*)d_ws;                 // 67.1 MB
    unsigned short* w_bf = x_bf + (size_t)M_DIM * K_DIM;          // 33.6 MB

    // x: 16384 blocks; w: 8192 blocks -> one fused dispatch
    cvt_fused_kernel<<<24576, 256, 0, stream>>>(
        (const float4*)x, (const float4*)wq, scales,
        (s16x8*)x_bf, (s16x8*)w_bf);

    dim3 grid(N_DIM / 128, M_DIM / 128);   // (32, 64)
    gemm_bt_kernel<<<grid, 256, 0, stream>>>(x_bf, w_bf, bias, out);
}

// Round 3
// 566.189 us; speedup vs baseline: 1.0073x; 1.0073x over previous
//
#include <hip/hip_runtime.h>

// y[b,s,n] = sum_k x[b,s,k] * (wq[n,k]*scale[blk]) + bias[n]
// M = 8192, N = 4096, K = 4096, fp32 in/out.
// R3: stride-1 coalesced convert (R2's stride-2 float4 pattern ran at 1.4 TB/s);
// GEMM reverted to R1's BK=32 (BK=64 was neutral/worse: occupancy 29->22%).

#define M_DIM 8192
#define N_DIM 4096
#define K_DIM 4096

typedef short s16x8 __attribute__((ext_vector_type(8)));   // 8 bf16 in 4 VGPRs
typedef float f32x4 __attribute__((ext_vector_type(4)));

__device__ __forceinline__ unsigned short f32_to_bf16(float f) {
    unsigned int u = __float_as_uint(f);
    unsigned int r = (u + 0x7fffu + ((u >> 16) & 1u)) >> 16;   // RNE
    return (unsigned short)r;
}

__device__ __forceinline__ ushort4 pack4(float4 a) {
    ushort4 r;
    r.x = f32_to_bf16(a.x); r.y = f32_to_bf16(a.y);
    r.z = f32_to_bf16(a.z); r.w = f32_to_bf16(a.w);
    return r;
}

// ---- fused pre-pass, fully stride-1 coalesced ----
// blocks [0,16384): x fp32->bf16, 512 float4/block (2 lane-contiguous loads)
// blocks [16384,24576): w dequant fp32*scale->bf16, same pattern
__global__ __launch_bounds__(256) void cvt_fused_kernel(
    const float4* __restrict__ x, const float4* __restrict__ wq,
    const float* __restrict__ scales,
    ushort4* __restrict__ xo, ushort4* __restrict__ wo) {
    const int b = blockIdx.x;
    const int t = threadIdx.x;
    if (b < 16384) {
        const int base = b * 512 + t;
#pragma unroll
        for (int j = 0; j < 2; ++j) {
            const int idx = base + j * 256;      // lane-contiguous per j
            xo[idx] = pack4(x[idx]);
        }
    } else {
        const int base = (b - 16384) * 512 + t;
#pragma unroll
        for (int j = 0; j < 2; ++j) {
            const int idx = base + j * 256;      // lane-contiguous per j
            const float s = scales[idx >> 5];    // 4*idx/128
            float4 a = wq[idx];
            a.x *= s; a.y *= s; a.z *= s; a.w *= s;
            wo[idx] = pack4(a);
        }
    }
}

// ---- async 16B global -> LDS ----
__device__ __forceinline__ void async_copy16(const unsigned short* g, unsigned short* l) {
    __builtin_amdgcn_global_load_lds(
        (const __attribute__((address_space(1))) unsigned int*)g,
        (__attribute__((address_space(3))) unsigned int*)l,
        16, 0, 0);
}

// ---- GEMM: C[M,N] = A[M,K](bf16) * B[N,K]^T(bf16) + bias ----
// 256 thr = 4 waves 2x2 over 128x128 tile; wave: 4x4 of 16x16x32 MFMA.
// BK=32, single-buffered LDS (R1 config: 345 us, MfmaUtil 35%, occ 29%).
__global__ __launch_bounds__(256) void gemm_bt_kernel(
    const unsigned short* __restrict__ A,   // M x K bf16 bits
    const unsigned short* __restrict__ B,   // N x K bf16 bits
    const float* __restrict__ bias,         // N
    float* __restrict__ C)                  // M x N
{
    __shared__ unsigned short lds_a[128 * 32];   // 8 KB
    __shared__ unsigned short lds_b[128 * 32];   // 8 KB

    const int t = threadIdx.x;
    const int w = t >> 6;
    const int l = t & 63;
    const int m0 = blockIdx.y * 128;
    const int n0 = blockIdx.x * 128;
    const int wm = (w & 1) * 64;
    const int wn = (w >> 1) * 64;

    const int srow = t >> 2;
    const int scol = (t & 3) * 8;
    const unsigned short* gA = A + (long)(m0 + srow) * K_DIM + scol;
    const unsigned short* gB = B + (long)(n0 + srow) * K_DIM + scol;
    unsigned short* lA = lds_a + t * 8;
    unsigned short* lB = lds_b + t * 8;

    // fragment addressing (measured m89/m91): row = base+(l&15), k = (l>>4)*8 + j
    const int fr = l & 15;
    const int fc = (l >> 4) * 8;

    f32x4 acc[4][4] = {};

    for (int kt = 0; kt < K_DIM / 32; ++kt) {
        const unsigned short* ga = gA + kt * 32;
        const unsigned short* gb = gB + kt * 32;
        async_copy16(ga,              lA);
        async_copy16(ga + 64 * K_DIM, lA + 2048);
        async_copy16(gb,              lB);
        async_copy16(gb + 64 * K_DIM, lB + 2048);
        __syncthreads();

        s16x8 af[4], bf[4];
#pragma unroll
        for (int i = 0; i < 4; ++i)
            af[i] = *(const s16x8*)(lds_a + (wm + i * 16 + fr) * 32 + fc);
#pragma unroll
        for (int j = 0; j < 4; ++j)
            bf[j] = *(const s16x8*)(lds_b + (wn + j * 16 + fr) * 32 + fc);

#pragma unroll
        for (int i = 0; i < 4; ++i)
#pragma unroll
            for (int j = 0; j < 4; ++j)
                acc[i][j] = __builtin_amdgcn_mfma_f32_16x16x32_bf16(
                    af[i], bf[j], acc[i][j], 0, 0, 0);
        __syncthreads();
    }

    // epilogue: C/D layout row=(l>>4)*4+reg, col=l&15 (measured m89/m91)
    const int q = l >> 4;
#pragma unroll
    for (int j = 0; j < 4; ++j) {
        const int col = n0 + wn + j * 16 + (l & 15);
        const float bv = bias[col];
#pragma unroll
        for (int i = 0; i < 4; ++i) {
            const int row = m0 + wm + i * 16 + q * 4;
#pragma unroll
            for (int r = 0; r < 4; ++r) {
                C[(long)(row + r) * N_DIM + col] = acc[i][j][r] + bv;
            }
        }
    }
}

extern "C" void kernel_launch(void* const* d_in, const int* in_sizes, int n_in,
                              void* d_out, int out_size, void* d_ws, size_t ws_size,
                              hipStream_t stream) {
    const float* x      = (const float*)d_in[0];
    const float* wq     = (const float*)d_in[1];
    const float* scales = (const float*)d_in[2];
    const float* bias   = (const float*)d_in[3];
    float* out = (float*)d_out;

    unsigned short* x_bf = (unsigned short*)d_ws;                 // 67.1 MB
    unsigned short* w_bf = x_bf + (size_t)M_DIM * K_DIM;          // 33.6 MB

    cvt_fused_kernel<<<24576, 256, 0, stream>>>(
        (const float4*)x, (const float4*)wq, scales,
        (ushort4*)x_bf, (ushort4*)w_bf);

    dim3 grid(N_DIM / 128, M_DIM / 128);   // (32, 64)
    gemm_bt_kernel<<<grid, 256, 0, stream>>>(x_bf, w_bf, bias, out);
}